// Round 2
// baseline (601.106 us; speedup 1.0000x reference)
//
#include <hip/hip_runtime.h>
#include <hip/hip_bf16.h>
#include <cstdint>
#include <cstddef>

// Problem dims
#define M_ROWS   4096     // B*T
#define N_VOCAB  32000    // V
#define K_DIM    512      // D
#define S_DIM    400
#define CV_DIM   600
#define OUT_PITCH 32600   // V + CV
#define PAD_IDX  1

typedef __attribute__((ext_vector_type(8))) short short8;
typedef __attribute__((ext_vector_type(8))) unsigned short ushort8;
typedef __attribute__((ext_vector_type(4))) float f32x4;

// ws layout
#define WB_OFF   0ull                       // W bf16: 32,768,000 B
#define HB_OFF   32768000ull                // hidden bf16: 4,194,304 B
#define COPYG_OFF 36962304ull
#define RSUM_OFF  36978688ull
#define SSCALE_OFF 36995072ull
#define SRCID_OFF 37011456ull               // 51,200 B
#define EB_OFF    37062656ull               // bf16 exp intermediate: 262,144,000 B
#define WS_NEED_BF16 (EB_OFF + 262144000ull)

__device__ inline void gload_lds16(const void* g, void* l) {
  __builtin_amdgcn_global_load_lds(
      (const __attribute__((address_space(1))) unsigned int*)g,
      (__attribute__((address_space(3))) unsigned int*)l, 16, 0, 0);
}

__device__ inline unsigned short f32_to_bf16_rn(float f) {
  unsigned u = __float_as_uint(f);
  u += 0x7FFFu + ((u >> 16) & 1u);
  return (unsigned short)(u >> 16);
}
__device__ inline float bf16_to_f32(unsigned short h) {
  return __uint_as_float((unsigned)h << 16);
}

// ---------- K1a: fp32 -> bf16 conversion (vectorized) ----------
__global__ void cvt_kernel(const float4* __restrict__ in, ushort4* __restrict__ out, unsigned n4) {
  unsigned stride = gridDim.x * blockDim.x;
  for (unsigned i = blockIdx.x * blockDim.x + threadIdx.x; i < n4; i += stride) {
    float4 v = in[i];
    ushort4 o;
    o.x = f32_to_bf16_rn(v.x);
    o.y = f32_to_bf16_rn(v.y);
    o.z = f32_to_bf16_rn(v.z);
    o.w = f32_to_bf16_rn(v.w);
    out[i] = o;
  }
}

// ---------- K1b: copy gate = sigmoid(hidden @ w_copy + b_copy), one wave/row ----------
__global__ void copygate_kernel(const float* __restrict__ hidden, const float* __restrict__ w_copy,
                                const float* __restrict__ b_copy, float* __restrict__ copyg) {
  unsigned gw = (blockIdx.x * blockDim.x + threadIdx.x) >> 6;   // row
  unsigned lane = threadIdx.x & 63u;
  if (gw >= M_ROWS) return;
  const float4* h4 = (const float4*)(hidden + (size_t)gw * K_DIM);
  const float4* w4 = (const float4*)w_copy;
  float dot = 0.f;
  #pragma unroll
  for (int i = 0; i < 2; ++i) {
    float4 a = h4[lane * 2 + i], w = w4[lane * 2 + i];
    dot += a.x * w.x + a.y * w.y + a.z * w.z + a.w * w.w;
  }
  #pragma unroll
  for (int mask = 1; mask < 64; mask <<= 1) dot += __shfl_xor(dot, mask);
  if (lane == 0) copyg[gw] = 1.f / (1.f + __expf(-(dot + b_copy[0])));
}

// ---------- K1c: recover src_ids from one-hot src_map, one wave/(b,s) ----------
__global__ void srcids_kernel(const float* __restrict__ src_map, int* __restrict__ src_ids) {
  unsigned pos = (blockIdx.x * blockDim.x + threadIdx.x) >> 6;  // b*S + s, 12800 total
  unsigned lane = threadIdx.x & 63u;
  if (pos >= 32 * S_DIM) return;
  const float* row = src_map + (size_t)pos * CV_DIM;
  int found = 1 << 30;
  for (int v = lane; v < CV_DIM; v += 64)
    if (row[v] > 0.5f) found = v;
  #pragma unroll
  for (int mask = 1; mask < 64; mask <<= 1) {
    int o = __shfl_xor(found, mask);
    found = found < o ? found : o;
  }
  if (lane == 0) src_ids[pos] = found;
}

// ---------- K2: bf16 MFMA GEMM (C = A * B^T) + exp epilogue + row-sum atomics ----------
// 256x256 tile, BK=64, 8 waves (2M x 4N), each wave 128x64 via 8x4 frags of 16x16x32.
// BF16OUT=1: pack exp to bf16 via LDS (XOR-swizzled), coalesced store to Eb.
// BF16OUT=0: direct fp32 store to out (fallback when ws too small).
template<int BF16OUT>
__global__ __launch_bounds__(512, 2)
void gemm_exp_kernel(const unsigned short* __restrict__ A,
                     const unsigned short* __restrict__ B,
                     const float* __restrict__ bias,
                     float* __restrict__ out,
                     unsigned short* __restrict__ Eb,
                     float* __restrict__ row_sum) {
  __shared__ unsigned short smem[2 * 256 * 64];   // 64 KB: As | Bs (K loop), repack buf (epilogue)
  unsigned short* As = smem;
  unsigned short* Bs = smem + 256 * 64;

  unsigned bid = blockIdx.x;
  // bijective XCD swizzle: 2000 blocks, 2000 % 8 == 0
  unsigned wg = (bid & 7u) * 250u + (bid >> 3);
  unsigned mt = wg / 125u, nt = wg % 125u;
  unsigned m0 = mt * 256u, n0 = nt * 256u;
  unsigned tid = threadIdx.x;
  unsigned lane = tid & 63u;
  unsigned wid = tid >> 6;
  unsigned wm = wid >> 2, wn = wid & 3u;     // 2 x 4 wave grid
  unsigned lr = lane >> 4, lc = lane & 15u;

  // staging addresses (tid-derived, kt-invariant)
  const unsigned short* Asrc[4];
  const unsigned short* Bsrc[4];
  unsigned soff[4];
  #pragma unroll
  for (unsigned i = 0; i < 4; ++i) {
    unsigned off = i * 8192u + tid * 16u;    // byte offset into 32KB half
    unsigned row = off >> 7;                 // 128 B per row
    unsigned col = (off & 127u) >> 1;        // bf16 col
    soff[i] = off;
    Asrc[i] = A + (size_t)(m0 + row) * K_DIM + col;
    Bsrc[i] = B + (size_t)(n0 + row) * K_DIM + col;
  }
  // LDS read base offsets (ushort index)
  unsigned aoff[8], boff[4];
  #pragma unroll
  for (int m = 0; m < 8; ++m) aoff[m] = (wm * 128u + m * 16u + lc) * 64u + lr * 8u;
  #pragma unroll
  for (int n = 0; n < 4; ++n) boff[n] = (wn * 64u + n * 16u + lc) * 64u + lr * 8u;

  f32x4 acc[8][4] = {};

  for (unsigned kt = 0; kt < 8; ++kt) {
    unsigned k0 = kt * 64u;
    #pragma unroll
    for (unsigned i = 0; i < 4; ++i) {
      gload_lds16(Asrc[i] + k0, (char*)As + soff[i]);
      gload_lds16(Bsrc[i] + k0, (char*)Bs + soff[i]);
    }
    __syncthreads();   // compiler emits vmcnt(0) drain before barrier
    #pragma unroll
    for (unsigned ks = 0; ks < 2; ++ks) {
      short8 af[8], bf[4];
      #pragma unroll
      for (int m = 0; m < 8; ++m) af[m] = *(const short8*)&As[aoff[m] + ks * 32u];
      #pragma unroll
      for (int n = 0; n < 4; ++n) bf[n] = *(const short8*)&Bs[boff[n] + ks * 32u];
      #pragma unroll
      for (int m = 0; m < 8; ++m)
        #pragma unroll
        for (int n = 0; n < 4; ++n)
          acc[m][n] = __builtin_amdgcn_mfma_f32_16x16x32_bf16(af[m], bf[n], acc[m][n], 0, 0, 0);
    }
    __syncthreads();
  }

  // epilogue: e = exp(logit + bias); |logit| <~ 4 so no max-subtraction needed.
  float bv[4];
  #pragma unroll
  for (int n = 0; n < 4; ++n) bv[n] = bias[n0 + wn * 64u + n * 16u + lc];

  // exp in place + per-row partial sums (atomics)
  #pragma unroll
  for (int m = 0; m < 8; ++m) {
    #pragma unroll
    for (int j = 0; j < 4; ++j) {
      unsigned grow = m0 + wm * 128u + m * 16u + lr * 4u + j;
      float rs = 0.f;
      #pragma unroll
      for (int n = 0; n < 4; ++n) {
        unsigned gcol = n0 + wn * 64u + n * 16u + lc;
        float e = (gcol == PAD_IDX) ? 0.f : __expf(acc[m][n][j] + bv[n]);
        acc[m][n][j] = e;
        rs += e;
      }
      #pragma unroll
      for (int mask = 1; mask < 16; mask <<= 1) rs += __shfl_xor(rs, mask);
      if (lc == 0) atomicAdd(&row_sum[grow], rs);
    }
  }

  if (BF16OUT) {
    // pack to bf16 via LDS (two 256x128 half-tiles), coalesced dwordx4 stores.
    // LDS layout XOR-swizzled: element (r, c) at smem[r*128 + (c ^ ((r&7)<<3))]
    #pragma unroll 1
    for (unsigned cpass = 0; cpass < 2; ++cpass) {
      if ((wn >> 1) == cpass) {
        #pragma unroll
        for (int m = 0; m < 8; ++m)
          #pragma unroll
          for (int j = 0; j < 4; ++j) {
            unsigned r = wm * 128u + m * 16u + lr * 4u + j;
            #pragma unroll
            for (int n = 0; n < 4; ++n) {
              unsigned c = (wn & 1u) * 64u + n * 16u + lc;
              smem[r * 128u + (c ^ ((r & 7u) << 3))] = f32_to_bf16_rn(acc[m][n][j]);
            }
          }
      }
      __syncthreads();
      {
        unsigned r = tid >> 1, c0 = (tid & 1u) * 64u;
        unsigned short* gdst = Eb + (size_t)(m0 + r) * N_VOCAB + n0 + cpass * 128u + c0;
        #pragma unroll
        for (unsigned q = 0; q < 8; ++q) {
          ushort8 v = *(const ushort8*)&smem[r * 128u + c0 + ((q ^ (r & 7u)) << 3)];
          *(ushort8*)(gdst + q * 8u) = v;
        }
      }
      __syncthreads();
    }
  } else {
    // fallback: direct fp32 stores of unnormalized exp into out
    #pragma unroll
    for (int m = 0; m < 8; ++m)
      #pragma unroll
      for (int j = 0; j < 4; ++j) {
        unsigned grow = m0 + wm * 128u + m * 16u + lr * 4u + j;
        #pragma unroll
        for (int n = 0; n < 4; ++n) {
          unsigned gcol = n0 + wn * 64u + n * 16u + lc;
          out[(size_t)grow * OUT_PITCH + gcol] = acc[m][n][j];
        }
      }
  }
}

// ---------- K2b: s[r] = (1 - copy[r]) / row_sum[r] ----------
__global__ void finalize_kernel(const float* __restrict__ row_sum, const float* __restrict__ copyg,
                                float* __restrict__ sscale) {
  unsigned r = blockIdx.x * blockDim.x + threadIdx.x;
  if (r < M_ROWS) sscale[r] = (1.f - copyg[r]) / row_sum[r];
}

// ---------- K3a: scale from bf16 intermediate -> fp32 out ----------
__global__ void scale_bf16_kernel(const unsigned short* __restrict__ Eb,
                                  const float* __restrict__ sscale,
                                  float* __restrict__ out) {
  unsigned row = blockIdx.y;
  unsigned c8 = blockIdx.x * blockDim.x + threadIdx.x;
  if (c8 >= N_VOCAB / 8) return;
  float s = sscale[row];
  ushort8 v = *(const ushort8*)(Eb + (size_t)row * N_VOCAB + c8 * 8u);
  float4 lo, hi;
  lo.x = bf16_to_f32(v[0]) * s; lo.y = bf16_to_f32(v[1]) * s;
  lo.z = bf16_to_f32(v[2]) * s; lo.w = bf16_to_f32(v[3]) * s;
  hi.x = bf16_to_f32(v[4]) * s; hi.y = bf16_to_f32(v[5]) * s;
  hi.z = bf16_to_f32(v[6]) * s; hi.w = bf16_to_f32(v[7]) * s;
  float4* o = (float4*)(out + (size_t)row * OUT_PITCH + c8 * 8u);
  o[0] = lo; o[1] = hi;
}

// ---------- K3b: in-place scale of generation region (fallback) ----------
__global__ void scale_kernel(float4* __restrict__ out, const float* __restrict__ sscale) {
  const unsigned total = M_ROWS * (N_VOCAB / 4);
  unsigned stride = gridDim.x * blockDim.x;
  for (unsigned i = blockIdx.x * blockDim.x + threadIdx.x; i < total; i += stride) {
    unsigned r = i / (N_VOCAB / 4);
    unsigned c = i % (N_VOCAB / 4);
    float s = sscale[r];
    float4 v = out[(size_t)r * (OUT_PITCH / 4) + c];
    v.x *= s; v.y *= s; v.z *= s; v.w *= s;
    out[(size_t)r * (OUT_PITCH / 4) + c] = v;
  }
}

// ---------- K4: copy branch scatter into extended vocab ----------
__global__ void copyprob_kernel(const float* __restrict__ attn, const int* __restrict__ src_ids,
                                const float* __restrict__ copyg, float* __restrict__ out) {
  unsigned r = blockIdx.x;           // 0..4095
  unsigned tid = threadIdx.x;        // 128 threads
  __shared__ float cp[CV_DIM];
  for (unsigned v = tid; v < CV_DIM; v += 128) cp[v] = 0.f;
  __syncthreads();
  unsigned batch = r >> 7;           // r / T
  float g = copyg[r];
  for (unsigned s = tid; s < S_DIM; s += 128) {
    float a = attn[(size_t)r * S_DIM + s] * g;
    atomicAdd(&cp[src_ids[batch * S_DIM + s]], a);
  }
  __syncthreads();
  for (unsigned v = tid; v < CV_DIM; v += 128)
    out[(size_t)r * OUT_PITCH + N_VOCAB + v] = cp[v];
}

extern "C" void kernel_launch(void* const* d_in, const int* in_sizes, int n_in,
                              void* d_out, int out_size, void* d_ws, size_t ws_size,
                              hipStream_t stream) {
  const float* hidden    = (const float*)d_in[0];   // [4096,512]
  const float* copy_attn = (const float*)d_in[1];   // [4096,400]
  const float* src_map   = (const float*)d_in[2];   // [32,400,600]
  const float* W         = (const float*)d_in[3];   // [32000,512]
  const float* bias      = (const float*)d_in[4];   // [32000]
  const float* w_copy    = (const float*)d_in[5];   // [512]
  const float* b_copy    = (const float*)d_in[6];   // [1]
  float* out = (float*)d_out;

  char* ws = (char*)d_ws;
  unsigned short* Wb = (unsigned short*)(ws + WB_OFF);
  unsigned short* Hb = (unsigned short*)(ws + HB_OFF);
  float* copyg   = (float*)(ws + COPYG_OFF);
  float* row_sum = (float*)(ws + RSUM_OFF);
  float* sscale  = (float*)(ws + SSCALE_OFF);
  int*   src_ids = (int*)(ws + SRCID_OFF);
  unsigned short* Eb = (unsigned short*)(ws + EB_OFF);

  const bool bf16_path = (ws_size >= WS_NEED_BF16);

  hipMemsetAsync(row_sum, 0, M_ROWS * sizeof(float), stream);

  cvt_kernel<<<2048, 256, 0, stream>>>((const float4*)W, (ushort4*)Wb,
                                       (unsigned)(N_VOCAB * K_DIM / 4));
  cvt_kernel<<<1024, 256, 0, stream>>>((const float4*)hidden, (ushort4*)Hb,
                                       (unsigned)(M_ROWS * K_DIM / 4));
  copygate_kernel<<<M_ROWS / 4, 256, 0, stream>>>(hidden, w_copy, b_copy, copyg);
  srcids_kernel<<<(32 * S_DIM) / 4, 256, 0, stream>>>(src_map, src_ids);

  // main GEMM: 16 x 125 tiles of 256x256, 512 threads
  if (bf16_path) {
    gemm_exp_kernel<1><<<(M_ROWS / 256) * (N_VOCAB / 256), 512, 0, stream>>>(
        Hb, Wb, bias, out, Eb, row_sum);
  } else {
    gemm_exp_kernel<0><<<(M_ROWS / 256) * (N_VOCAB / 256), 512, 0, stream>>>(
        Hb, Wb, bias, out, Eb, row_sum);
  }

  finalize_kernel<<<(M_ROWS + 255) / 256, 256, 0, stream>>>(row_sum, copyg, sscale);

  if (bf16_path) {
    dim3 g(16, M_ROWS);
    scale_bf16_kernel<<<g, 256, 0, stream>>>(Eb, sscale, out);
  } else {
    scale_kernel<<<4096, 256, 0, stream>>>((float4*)out, sscale);
  }

  copyprob_kernel<<<M_ROWS, 128, 0, stream>>>(copy_attn, src_ids, copyg, out);
}

// Round 3
// 561.648 us; speedup vs baseline: 1.0703x; 1.0703x over previous
//
#include <hip/hip_runtime.h>
#include <hip/hip_bf16.h>
#include <cstdint>
#include <cstddef>

// Problem dims
#define M_ROWS   4096     // B*T
#define N_VOCAB  32000    // V
#define K_DIM    512      // D
#define S_DIM    400
#define CV_DIM   600
#define OUT_PITCH 32600   // V + CV
#define PAD_IDX  1

typedef __attribute__((ext_vector_type(8))) short short8;
typedef __attribute__((ext_vector_type(8))) unsigned short ushort8;
typedef __attribute__((ext_vector_type(4))) float f32x4;

// ws layout
#define WB_OFF   0ull                       // W bf16: 32,768,000 B
#define HB_OFF   32768000ull                // hidden bf16: 4,194,304 B
#define COPYG_OFF 36962304ull
#define RSUM_OFF  36978688ull
#define SSCALE_OFF 36995072ull
#define SRCID_OFF 37011456ull               // 51,200 B
#define EB_OFF    37062656ull               // bf16 exp intermediate: 262,144,000 B
#define WS_NEED_BF16 (EB_OFF + 262144000ull)

__device__ inline void gload_lds16(const void* g, void* l) {
  __builtin_amdgcn_global_load_lds(
      (const __attribute__((address_space(1))) unsigned int*)g,
      (__attribute__((address_space(3))) unsigned int*)l, 16, 0, 0);
}

__device__ inline unsigned short f32_to_bf16_rn(float f) {
  unsigned u = __float_as_uint(f);
  u += 0x7FFFu + ((u >> 16) & 1u);
  return (unsigned short)(u >> 16);
}
__device__ inline float bf16_to_f32(unsigned short h) {
  return __uint_as_float((unsigned)h << 16);
}

// ---------- K1a: fp32 -> bf16 conversion (vectorized) ----------
__global__ void cvt_kernel(const float4* __restrict__ in, ushort4* __restrict__ out, unsigned n4) {
  unsigned stride = gridDim.x * blockDim.x;
  for (unsigned i = blockIdx.x * blockDim.x + threadIdx.x; i < n4; i += stride) {
    float4 v = in[i];
    ushort4 o;
    o.x = f32_to_bf16_rn(v.x);
    o.y = f32_to_bf16_rn(v.y);
    o.z = f32_to_bf16_rn(v.z);
    o.w = f32_to_bf16_rn(v.w);
    out[i] = o;
  }
}

// ---------- K1b: copy gate ----------
__global__ void copygate_kernel(const float* __restrict__ hidden, const float* __restrict__ w_copy,
                                const float* __restrict__ b_copy, float* __restrict__ copyg) {
  unsigned gw = (blockIdx.x * blockDim.x + threadIdx.x) >> 6;
  unsigned lane = threadIdx.x & 63u;
  if (gw >= M_ROWS) return;
  const float4* h4 = (const float4*)(hidden + (size_t)gw * K_DIM);
  const float4* w4 = (const float4*)w_copy;
  float dot = 0.f;
  #pragma unroll
  for (int i = 0; i < 2; ++i) {
    float4 a = h4[lane * 2 + i], w = w4[lane * 2 + i];
    dot += a.x * w.x + a.y * w.y + a.z * w.z + a.w * w.w;
  }
  #pragma unroll
  for (int mask = 1; mask < 64; mask <<= 1) dot += __shfl_xor(dot, mask);
  if (lane == 0) copyg[gw] = 1.f / (1.f + __expf(-(dot + b_copy[0])));
}

// ---------- K1c: recover src_ids from one-hot src_map ----------
__global__ void srcids_kernel(const float* __restrict__ src_map, int* __restrict__ src_ids) {
  unsigned pos = (blockIdx.x * blockDim.x + threadIdx.x) >> 6;
  unsigned lane = threadIdx.x & 63u;
  if (pos >= 32 * S_DIM) return;
  const float* row = src_map + (size_t)pos * CV_DIM;
  int found = 1 << 30;
  for (int v = lane; v < CV_DIM; v += 64)
    if (row[v] > 0.5f) found = v;
  #pragma unroll
  for (int mask = 1; mask < 64; mask <<= 1) {
    int o = __shfl_xor(found, mask);
    found = found < o ? found : o;
  }
  if (lane == 0) src_ids[pos] = found;
}

// ---------- K2: 256x256 8-phase bf16 MFMA GEMM + exp epilogue ----------
// m201-style template: BK=64, 8 waves (2M x 4N), 128 KB LDS double-buffer,
// st-swizzled LDS (chunk ^= row&7, both-sides), 4 phases per K-step,
// counted vmcnt(4), setprio around MFMA clusters.
template<int BF16OUT>
__global__ __launch_bounds__(512, 2)
void gemm_exp_kernel(const unsigned short* __restrict__ A,
                     const unsigned short* __restrict__ B,
                     const float* __restrict__ bias,
                     float* __restrict__ out,
                     unsigned short* __restrict__ Eb,
                     float* __restrict__ row_sum) {
  // [buf:2][op:2][half:2][row:128][chunk:8 swz][8 ushort] = 128 KB
  __shared__ unsigned short smem[65536];

  unsigned bid = blockIdx.x;
  // bijective XCD swizzle: 2000 blocks, 2000 % 8 == 0
  unsigned wg = (bid & 7u) * 250u + (bid >> 3);
  unsigned mt = wg / 125u, nt = wg % 125u;
  unsigned m0 = mt * 256u, n0 = nt * 256u;
  unsigned tid = threadIdx.x;
  unsigned lane = tid & 63u;
  unsigned wid = tid >> 6;
  unsigned wm = wid >> 2, wn = wid & 3u;     // 2 x 4 wave grid
  unsigned lr = lane >> 4, lc = lane & 15u;

  // swizzled read chunk offsets (ushort units) for ks=0/1
  const unsigned ch0 = (lr ^ (lc & 7u)) * 8u;
  const unsigned ch1 = ((lr + 4u) ^ (lc & 7u)) * 8u;

  f32x4 acc[8][4] = {};
  short8 aw[4][2], bw0[2][2], bw1[2][2];

  // ---- staging: unit-partitioned so phase needs match issue order ----
  // A unit u: rows [u*64,u*64+64) of BOTH 128-row halves (what quadrant mh=u reads)
  auto STAGE_A = [&](unsigned nb, unsigned u, unsigned kt) {
    unsigned rr = tid >> 3;                        // 0..63
    unsigned ch = (tid & 7u) ^ (rr & 7u);          // inverse-swizzled source chunk
    const unsigned short* s0 = A + (size_t)(m0 + u * 64u + rr) * K_DIM + kt * 64u + ch * 8u;
    char* d = (char*)smem + nb * 65536u + u * 8192u + (size_t)tid * 16u;
    gload_lds16(s0, d);                                    // half 0 (wm=0)
    gload_lds16(s0 + (size_t)128u * K_DIM, d + 16384u);    // half 1 (wm=1)
  };
  // B unit v: the nh=v fragment rows: [v*32,+32) and [64+v*32,+32) of both halves
  auto STAGE_B = [&](unsigned nb, unsigned v, unsigned kt) {
    unsigned rr = (tid >> 3) & 31u;                // 0..31
    unsigned ch = (tid & 7u) ^ (rr & 7u);
    unsigned sb = (tid >> 8) & 1u;                 // which 64-row block within half
    unsigned grow = sb * 64u + v * 32u + rr;
    const unsigned short* s0 = B + (size_t)(n0 + grow) * K_DIM + kt * 64u + ch * 8u;
    char* d = (char*)smem + nb * 65536u + 32768u + sb * 8192u + v * 4096u
              + (size_t)(tid & 255u) * 16u;
    gload_lds16(s0, d);                                    // half 0
    gload_lds16(s0 + (size_t)128u * K_DIM, d + 16384u);    // half 1
  };

  auto LDA = [&](unsigned buf, int mh) {
    #pragma unroll
    for (int mm = 0; mm < 4; ++mm) {
      unsigned ridx = buf * 32768u + wm * 8192u + ((unsigned)(mh * 4 + mm) * 16u + lc) * 64u;
      aw[mm][0] = *(const short8*)&smem[ridx + ch0];
      aw[mm][1] = *(const short8*)&smem[ridx + ch1];
    }
  };
  auto LDB = [&](short8 (&bw)[2][2], unsigned buf, int nh) {
    #pragma unroll
    for (int nn = 0; nn < 2; ++nn) {
      unsigned n = (unsigned)(nh * 2 + nn);
      unsigned ridx = buf * 32768u + 16384u + (wn >> 1) * 8192u
                    + ((wn & 1u) * 64u + n * 16u + lc) * 64u;
      bw[nn][0] = *(const short8*)&smem[ridx + ch0];
      bw[nn][1] = *(const short8*)&smem[ridx + ch1];
    }
  };
  auto MMQ = [&](short8 (&bw)[2][2], int mh, int nh) {
    __builtin_amdgcn_s_setprio(1);
    #pragma unroll
    for (int mm = 0; mm < 4; ++mm)
      #pragma unroll
      for (int nn = 0; nn < 2; ++nn)
        #pragma unroll
        for (int ks = 0; ks < 2; ++ks)
          acc[mh * 4 + mm][nh * 2 + nn] = __builtin_amdgcn_mfma_f32_16x16x32_bf16(
              aw[mm][ks], bw[nn][ks], acc[mh * 4 + mm][nh * 2 + nn], 0, 0, 0);
    __builtin_amdgcn_s_setprio(0);
  };
  auto WAIT_LGKM = [&]() {
    asm volatile("s_waitcnt lgkmcnt(0)" ::: "memory");
    __builtin_amdgcn_sched_barrier(0);
  };

  // ---- prologue: stage tile 0 (FIFO: SA0,SB0,SB1,SA1), keep last 4 in flight
  STAGE_A(0, 0, 0);
  STAGE_B(0, 0, 0);
  STAGE_B(0, 1, 0);
  STAGE_A(0, 1, 0);
  asm volatile("s_waitcnt vmcnt(4)" ::: "memory");
  __builtin_amdgcn_s_barrier();

  #pragma unroll
  for (int kt = 0; kt < 8; ++kt) {
    const unsigned buf = (unsigned)kt & 1u;
    const unsigned nbuf = buf ^ 1u;
    // ---- p0: read A-mh0 + B-nh0, stage SA0(t+1), compute q(0,0)
    LDA(buf, 0);
    LDB(bw0, buf, 0);
    if (kt < 7) STAGE_A(nbuf, 0, kt + 1);
    __builtin_amdgcn_s_barrier();
    WAIT_LGKM();
    MMQ(bw0, 0, 0);
    if (kt < 7) asm volatile("s_waitcnt vmcnt(4)" ::: "memory");   // SB1(t) landed
    else        asm volatile("s_waitcnt vmcnt(2)" ::: "memory");
    __builtin_amdgcn_s_barrier();
    // ---- p1: read B-nh1, stage SB0(t+1), compute q(0,1)
    LDB(bw1, buf, 1);
    if (kt < 7) STAGE_B(nbuf, 0, kt + 1);
    __builtin_amdgcn_s_barrier();
    WAIT_LGKM();
    MMQ(bw1, 0, 1);
    if (kt < 7) asm volatile("s_waitcnt vmcnt(4)" ::: "memory");   // SA1(t) landed
    else        asm volatile("s_waitcnt vmcnt(0)" ::: "memory");
    __builtin_amdgcn_s_barrier();
    // ---- p2: read A-mh1, stage SB1(t+1), compute q(1,1)
    LDA(buf, 1);
    if (kt < 7) STAGE_B(nbuf, 1, kt + 1);
    __builtin_amdgcn_s_barrier();
    WAIT_LGKM();
    MMQ(bw1, 1, 1);
    __builtin_amdgcn_s_barrier();
    // ---- p3: stage SA1(t+1), compute q(1,0)
    if (kt < 7) STAGE_A(nbuf, 1, kt + 1);
    __builtin_amdgcn_s_barrier();
    WAIT_LGKM();
    MMQ(bw0, 1, 0);
    if (kt < 7) asm volatile("s_waitcnt vmcnt(4)" ::: "memory");   // SA0,SB0(t+1) landed
    __builtin_amdgcn_s_barrier();
  }

  // ---- epilogue: e = exp(logit + bias); |logit| <~ 4 so no max-subtraction.
  float bv[4];
  #pragma unroll
  for (int n = 0; n < 4; ++n) bv[n] = bias[n0 + wn * 64u + n * 16u + lc];

  #pragma unroll
  for (int m = 0; m < 8; ++m) {
    #pragma unroll
    for (int j = 0; j < 4; ++j) {
      unsigned grow = m0 + wm * 128u + m * 16u + lr * 4u + j;
      float rs = 0.f;
      #pragma unroll
      for (int n = 0; n < 4; ++n) {
        unsigned gcol = n0 + wn * 64u + n * 16u + lc;
        float e = (gcol == PAD_IDX) ? 0.f : __expf(acc[m][n][j] + bv[n]);
        acc[m][n][j] = e;
        rs += e;
      }
      #pragma unroll
      for (int mask = 1; mask < 16; mask <<= 1) rs += __shfl_xor(rs, mask);
      if (lc == 0) atomicAdd(&row_sum[grow], rs);
    }
  }

  if (BF16OUT) {
    // pack to bf16 via LDS (two 256x128 half-tiles), coalesced stores.
    // repack region = first 64 KB of smem (all K-loop reads retired by final barrier).
    #pragma unroll 1
    for (unsigned cpass = 0; cpass < 2; ++cpass) {
      if ((wn >> 1) == cpass) {
        #pragma unroll
        for (int m = 0; m < 8; ++m)
          #pragma unroll
          for (int j = 0; j < 4; ++j) {
            unsigned r = wm * 128u + m * 16u + lr * 4u + j;
            #pragma unroll
            for (int n = 0; n < 4; ++n) {
              unsigned c = (wn & 1u) * 64u + n * 16u + lc;
              smem[r * 128u + (c ^ ((r & 7u) << 3))] = f32_to_bf16_rn(acc[m][n][j]);
            }
          }
      }
      __syncthreads();
      {
        unsigned r = tid >> 1, c0 = (tid & 1u) * 64u;
        unsigned short* gdst = Eb + (size_t)(m0 + r) * N_VOCAB + n0 + cpass * 128u + c0;
        #pragma unroll
        for (unsigned q = 0; q < 8; ++q) {
          ushort8 v = *(const ushort8*)&smem[r * 128u + c0 + ((q ^ (r & 7u)) << 3)];
          *(ushort8*)(gdst + q * 8u) = v;
        }
      }
      __syncthreads();
    }
  } else {
    #pragma unroll
    for (int m = 0; m < 8; ++m)
      #pragma unroll
      for (int j = 0; j < 4; ++j) {
        unsigned grow = m0 + wm * 128u + m * 16u + lr * 4u + j;
        #pragma unroll
        for (int n = 0; n < 4; ++n) {
          unsigned gcol = n0 + wn * 64u + n * 16u + lc;
          out[(size_t)grow * OUT_PITCH + gcol] = acc[m][n][j];
        }
      }
  }
}

// ---------- K2b: s[r] = (1 - copy[r]) / row_sum[r] ----------
__global__ void finalize_kernel(const float* __restrict__ row_sum, const float* __restrict__ copyg,
                                float* __restrict__ sscale) {
  unsigned r = blockIdx.x * blockDim.x + threadIdx.x;
  if (r < M_ROWS) sscale[r] = (1.f - copyg[r]) / row_sum[r];
}

// ---------- K3a: scale from bf16 intermediate -> fp32 out ----------
__global__ void scale_bf16_kernel(const unsigned short* __restrict__ Eb,
                                  const float* __restrict__ sscale,
                                  float* __restrict__ out) {
  unsigned row = blockIdx.y;
  unsigned c8 = blockIdx.x * blockDim.x + threadIdx.x;
  if (c8 >= N_VOCAB / 8) return;
  float s = sscale[row];
  ushort8 v = *(const ushort8*)(Eb + (size_t)row * N_VOCAB + c8 * 8u);
  float4 lo, hi;
  lo.x = bf16_to_f32(v[0]) * s; lo.y = bf16_to_f32(v[1]) * s;
  lo.z = bf16_to_f32(v[2]) * s; lo.w = bf16_to_f32(v[3]) * s;
  hi.x = bf16_to_f32(v[4]) * s; hi.y = bf16_to_f32(v[5]) * s;
  hi.z = bf16_to_f32(v[6]) * s; hi.w = bf16_to_f32(v[7]) * s;
  float4* o = (float4*)(out + (size_t)row * OUT_PITCH + c8 * 8u);
  o[0] = lo; o[1] = hi;
}

// ---------- K3b: in-place scale (fallback) ----------
__global__ void scale_kernel(float4* __restrict__ out, const float* __restrict__ sscale) {
  const unsigned total = M_ROWS * (N_VOCAB / 4);
  unsigned stride = gridDim.x * blockDim.x;
  for (unsigned i = blockIdx.x * blockDim.x + threadIdx.x; i < total; i += stride) {
    unsigned r = i / (N_VOCAB / 4);
    unsigned c = i % (N_VOCAB / 4);
    float s = sscale[r];
    float4 v = out[(size_t)r * (OUT_PITCH / 4) + c];
    v.x *= s; v.y *= s; v.z *= s; v.w *= s;
    out[(size_t)r * (OUT_PITCH / 4) + c] = v;
  }
}

// ---------- K4: copy branch scatter ----------
__global__ void copyprob_kernel(const float* __restrict__ attn, const int* __restrict__ src_ids,
                                const float* __restrict__ copyg, float* __restrict__ out) {
  unsigned r = blockIdx.x;
  unsigned tid = threadIdx.x;
  __shared__ float cp[CV_DIM];
  for (unsigned v = tid; v < CV_DIM; v += 128) cp[v] = 0.f;
  __syncthreads();
  unsigned batch = r >> 7;
  float g = copyg[r];
  for (unsigned s = tid; s < S_DIM; s += 128) {
    float a = attn[(size_t)r * S_DIM + s] * g;
    atomicAdd(&cp[src_ids[batch * S_DIM + s]], a);
  }
  __syncthreads();
  for (unsigned v = tid; v < CV_DIM; v += 128)
    out[(size_t)r * OUT_PITCH + N_VOCAB + v] = cp[v];
}

extern "C" void kernel_launch(void* const* d_in, const int* in_sizes, int n_in,
                              void* d_out, int out_size, void* d_ws, size_t ws_size,
                              hipStream_t stream) {
  const float* hidden    = (const float*)d_in[0];
  const float* copy_attn = (const float*)d_in[1];
  const float* src_map   = (const float*)d_in[2];
  const float* W         = (const float*)d_in[3];
  const float* bias      = (const float*)d_in[4];
  const float* w_copy    = (const float*)d_in[5];
  const float* b_copy    = (const float*)d_in[6];
  float* out = (float*)d_out;

  char* ws = (char*)d_ws;
  unsigned short* Wb = (unsigned short*)(ws + WB_OFF);
  unsigned short* Hb = (unsigned short*)(ws + HB_OFF);
  float* copyg   = (float*)(ws + COPYG_OFF);
  float* row_sum = (float*)(ws + RSUM_OFF);
  float* sscale  = (float*)(ws + SSCALE_OFF);
  int*   src_ids = (int*)(ws + SRCID_OFF);
  unsigned short* Eb = (unsigned short*)(ws + EB_OFF);

  const bool bf16_path = (ws_size >= WS_NEED_BF16);

  hipMemsetAsync(row_sum, 0, M_ROWS * sizeof(float), stream);

  cvt_kernel<<<2048, 256, 0, stream>>>((const float4*)W, (ushort4*)Wb,
                                       (unsigned)(N_VOCAB * K_DIM / 4));
  cvt_kernel<<<1024, 256, 0, stream>>>((const float4*)hidden, (ushort4*)Hb,
                                       (unsigned)(M_ROWS * K_DIM / 4));
  copygate_kernel<<<M_ROWS / 4, 256, 0, stream>>>(hidden, w_copy, b_copy, copyg);
  srcids_kernel<<<(32 * S_DIM) / 4, 256, 0, stream>>>(src_map, src_ids);

  if (bf16_path) {
    gemm_exp_kernel<1><<<(M_ROWS / 256) * (N_VOCAB / 256), 512, 0, stream>>>(
        Hb, Wb, bias, out, Eb, row_sum);
  } else {
    gemm_exp_kernel<0><<<(M_ROWS / 256) * (N_VOCAB / 256), 512, 0, stream>>>(
        Hb, Wb, bias, out, Eb, row_sum);
  }

  finalize_kernel<<<(M_ROWS + 255) / 256, 256, 0, stream>>>(row_sum, copyg, sscale);

  if (bf16_path) {
    dim3 g(16, M_ROWS);
    scale_bf16_kernel<<<g, 256, 0, stream>>>(Eb, sscale, out);
  } else {
    scale_kernel<<<4096, 256, 0, stream>>>((float4*)out, sscale);
  }

  copyprob_kernel<<<M_ROWS, 128, 0, stream>>>(copy_attn, src_ids, copyg, out);
}

// Round 4
// 486.684 us; speedup vs baseline: 1.2351x; 1.1540x over previous
//
#include <hip/hip_runtime.h>
#include <hip/hip_bf16.h>
#include <cstdint>
#include <cstddef>

// Problem dims
#define M_ROWS   4096     // B*T
#define N_VOCAB  32000    // V
#define K_DIM    512      // D
#define S_DIM    400
#define CV_DIM   600
#define OUT_PITCH 32600   // V + CV
#define PAD_IDX  1

typedef __attribute__((ext_vector_type(8))) short short8;
typedef __attribute__((ext_vector_type(8))) unsigned short ushort8;
typedef __attribute__((ext_vector_type(4))) float f32x4;

// ws layout
#define WB_OFF   0ull                       // W bf16: 32,768,000 B
#define HB_OFF   32768000ull                // hidden bf16: 4,194,304 B
#define COPYG_OFF 36962304ull
#define RSUM_OFF  36978688ull
#define SSCALE_OFF 36995072ull
#define SRCID_OFF 37011456ull               // 51,200 B
#define EB_OFF    37062656ull               // bf16 exp intermediate: 262,144,000 B
#define WS_NEED_BF16 (EB_OFF + 262144000ull)

__device__ inline void gload_lds16(const void* g, void* l) {
  __builtin_amdgcn_global_load_lds(
      (const __attribute__((address_space(1))) unsigned int*)g,
      (__attribute__((address_space(3))) unsigned int*)l, 16, 0, 0);
}

__device__ inline unsigned short f32_to_bf16_rn(float f) {
  unsigned u = __float_as_uint(f);
  u += 0x7FFFu + ((u >> 16) & 1u);
  return (unsigned short)(u >> 16);
}
__device__ inline float bf16_to_f32(unsigned short h) {
  return __uint_as_float((unsigned)h << 16);
}

// ---------- K1a: fp32 -> bf16 conversion (vectorized) ----------
__global__ void cvt_kernel(const float4* __restrict__ in, ushort4* __restrict__ out, unsigned n4) {
  unsigned stride = gridDim.x * blockDim.x;
  for (unsigned i = blockIdx.x * blockDim.x + threadIdx.x; i < n4; i += stride) {
    float4 v = in[i];
    ushort4 o;
    o.x = f32_to_bf16_rn(v.x);
    o.y = f32_to_bf16_rn(v.y);
    o.z = f32_to_bf16_rn(v.z);
    o.w = f32_to_bf16_rn(v.w);
    out[i] = o;
  }
}

// ---------- K1b: copy gate ----------
__global__ void copygate_kernel(const float* __restrict__ hidden, const float* __restrict__ w_copy,
                                const float* __restrict__ b_copy, float* __restrict__ copyg) {
  unsigned gw = (blockIdx.x * blockDim.x + threadIdx.x) >> 6;
  unsigned lane = threadIdx.x & 63u;
  if (gw >= M_ROWS) return;
  const float4* h4 = (const float4*)(hidden + (size_t)gw * K_DIM);
  const float4* w4 = (const float4*)w_copy;
  float dot = 0.f;
  #pragma unroll
  for (int i = 0; i < 2; ++i) {
    float4 a = h4[lane * 2 + i], w = w4[lane * 2 + i];
    dot += a.x * w.x + a.y * w.y + a.z * w.z + a.w * w.w;
  }
  #pragma unroll
  for (int mask = 1; mask < 64; mask <<= 1) dot += __shfl_xor(dot, mask);
  if (lane == 0) copyg[gw] = 1.f / (1.f + __expf(-(dot + b_copy[0])));
}

// ---------- K1c: recover src_ids from one-hot src_map ----------
__global__ void srcids_kernel(const float* __restrict__ src_map, int* __restrict__ src_ids) {
  unsigned pos = (blockIdx.x * blockDim.x + threadIdx.x) >> 6;
  unsigned lane = threadIdx.x & 63u;
  if (pos >= 32 * S_DIM) return;
  const float* row = src_map + (size_t)pos * CV_DIM;
  int found = 1 << 30;
  for (int v = lane; v < CV_DIM; v += 64)
    if (row[v] > 0.5f) found = v;
  #pragma unroll
  for (int mask = 1; mask < 64; mask <<= 1) {
    int o = __shfl_xor(found, mask);
    found = found < o ? found : o;
  }
  if (lane == 0) src_ids[pos] = found;
}

// ---------- K2: m97-structure 128x128 bf16 MFMA GEMM + exp epilogue ----------
// 4 waves (2x2), BK=64, single 32 KB LDS, 2-barrier loop, T2 swizzled LDS,
// 3 blocks/CU for cross-block latency hiding (the m114 mechanism).
template<int BF16OUT>
__global__ __launch_bounds__(256, 3)
void gemm_exp_kernel(const unsigned short* __restrict__ A,
                     const unsigned short* __restrict__ B,
                     const float* __restrict__ bias,
                     float* __restrict__ out,
                     unsigned short* __restrict__ Eb,
                     float* __restrict__ row_sum) {
  // As/Bs: [128 rows][8 chunks swz][8 ushort] = 16 KB each; reused for epilogue pack.
  __shared__ unsigned short smem[16384];   // 32 KB
  unsigned short* As = smem;
  unsigned short* Bs = smem + 8192;

  unsigned bid = blockIdx.x;
  // bijective XCD swizzle: 8000 blocks, 8000 % 8 == 0
  unsigned wg = (bid & 7u) * 1000u + (bid >> 3);
  unsigned mt = wg / 250u, nt = wg % 250u;
  unsigned m0 = mt * 128u, n0 = nt * 128u;
  unsigned tid = threadIdx.x;
  unsigned lane = tid & 63u;
  unsigned wid = tid >> 6;
  unsigned wm = wid >> 1, wn = wid & 1u;    // 2 x 2 wave grid, 64x64 per wave
  unsigned lr = lane >> 4, lc = lane & 15u;

  // swizzled read chunk offsets (ushort units) for ks=0/1  (verified R3 pair)
  const unsigned ch0 = (lr ^ (lc & 7u)) * 8u;
  const unsigned ch1 = ((lr + 4u) ^ (lc & 7u)) * 8u;

  // staging sources (kt-invariant): unit u = i*256 + tid, rr = u>>3, inverse-swz chunk
  const unsigned short* Asrc[4];
  const unsigned short* Bsrc[4];
  unsigned dst[4];
  #pragma unroll
  for (unsigned i = 0; i < 4; ++i) {
    unsigned u = i * 256u + tid;
    unsigned rr = u >> 3;                       // 0..127
    unsigned ch = (u & 7u) ^ (rr & 7u);         // inverse-swizzled source chunk
    dst[i] = u * 16u;                           // linear dest byte offset
    Asrc[i] = A + (size_t)(m0 + rr) * K_DIM + ch * 8u;
    Bsrc[i] = B + (size_t)(n0 + rr) * K_DIM + ch * 8u;
  }
  // fragment read row bases (ushort index)
  unsigned arow[4], brow[4];
  #pragma unroll
  for (int m = 0; m < 4; ++m) arow[m] = (wm * 64u + m * 16u + lc) * 64u;
  #pragma unroll
  for (int n = 0; n < 4; ++n) brow[n] = (wn * 64u + n * 16u + lc) * 64u;

  f32x4 acc[4][4] = {};

  for (unsigned kt = 0; kt < 8; ++kt) {
    unsigned k0 = kt * 64u;
    #pragma unroll
    for (unsigned i = 0; i < 4; ++i) {
      gload_lds16(Asrc[i] + k0, (char*)As + dst[i]);
      gload_lds16(Bsrc[i] + k0, (char*)Bs + dst[i]);
    }
    __syncthreads();   // compiler emits vmcnt(0) drain before barrier
    {
      short8 af[4][2], bf[4][2];
      #pragma unroll
      for (int m = 0; m < 4; ++m) {
        af[m][0] = *(const short8*)&As[arow[m] + ch0];
        af[m][1] = *(const short8*)&As[arow[m] + ch1];
      }
      #pragma unroll
      for (int n = 0; n < 4; ++n) {
        bf[n][0] = *(const short8*)&Bs[brow[n] + ch0];
        bf[n][1] = *(const short8*)&Bs[brow[n] + ch1];
      }
      #pragma unroll
      for (int ks = 0; ks < 2; ++ks)
        #pragma unroll
        for (int m = 0; m < 4; ++m)
          #pragma unroll
          for (int n = 0; n < 4; ++n)
            acc[m][n] = __builtin_amdgcn_mfma_f32_16x16x32_bf16(af[m][ks], bf[n][ks],
                                                                acc[m][n], 0, 0, 0);
    }
    __syncthreads();
  }

  // epilogue: e = exp(logit + bias); |logit| <~ 4 so no max-subtraction.
  float bv[4];
  #pragma unroll
  for (int n = 0; n < 4; ++n) bv[n] = bias[n0 + wn * 64u + n * 16u + lc];

  #pragma unroll
  for (int m = 0; m < 4; ++m) {
    #pragma unroll
    for (int j = 0; j < 4; ++j) {
      unsigned grow = m0 + wm * 64u + m * 16u + lr * 4u + j;
      float rs = 0.f;
      #pragma unroll
      for (int n = 0; n < 4; ++n) {
        unsigned gcol = n0 + wn * 64u + n * 16u + lc;
        float e = (gcol == PAD_IDX) ? 0.f : __expf(acc[m][n][j] + bv[n]);
        acc[m][n][j] = e;
        rs += e;
      }
      #pragma unroll
      for (int mask = 1; mask < 16; mask <<= 1) rs += __shfl_xor(rs, mask);
      if (lc == 0) atomicAdd(&row_sum[grow], rs);
    }
  }

  if (BF16OUT) {
    // pack 128x128 bf16 tile via LDS (swizzled), coalesced stores to Eb.
    // smem reuse: last K-loop __syncthreads retired all LDS reads.
    #pragma unroll
    for (int m = 0; m < 4; ++m)
      #pragma unroll
      for (int j = 0; j < 4; ++j) {
        unsigned r = wm * 64u + m * 16u + lr * 4u + j;
        #pragma unroll
        for (int n = 0; n < 4; ++n) {
          unsigned c = wn * 64u + n * 16u + lc;
          smem[r * 128u + (c ^ ((r & 7u) << 3))] = f32_to_bf16_rn(acc[m][n][j]);
        }
      }
    __syncthreads();
    {
      unsigned r = tid >> 1, c0 = (tid & 1u) * 64u;
      unsigned short* gdst = Eb + (size_t)(m0 + r) * N_VOCAB + n0 + c0;
      #pragma unroll
      for (unsigned q = 0; q < 8; ++q) {
        ushort8 v = *(const ushort8*)&smem[r * 128u + c0 + ((q ^ (r & 7u)) << 3)];
        *(ushort8*)(gdst + q * 8u) = v;
      }
    }
  } else {
    #pragma unroll
    for (int m = 0; m < 4; ++m)
      #pragma unroll
      for (int j = 0; j < 4; ++j) {
        unsigned grow = m0 + wm * 64u + m * 16u + lr * 4u + j;
        #pragma unroll
        for (int n = 0; n < 4; ++n) {
          unsigned gcol = n0 + wn * 64u + n * 16u + lc;
          out[(size_t)grow * OUT_PITCH + gcol] = acc[m][n][j];
        }
      }
  }
}

// ---------- K2b: s[r] = (1 - copy[r]) / row_sum[r] ----------
__global__ void finalize_kernel(const float* __restrict__ row_sum, const float* __restrict__ copyg,
                                float* __restrict__ sscale) {
  unsigned r = blockIdx.x * blockDim.x + threadIdx.x;
  if (r < M_ROWS) sscale[r] = (1.f - copyg[r]) / row_sum[r];
}

// ---------- K3a: scale from bf16 intermediate -> fp32 out (dense stores) ----------
__global__ void scale_bf16_kernel(const unsigned short* __restrict__ Eb,
                                  const float* __restrict__ sscale,
                                  float* __restrict__ out) {
  unsigned row = blockIdx.y;
  unsigned c4 = blockIdx.x * blockDim.x + threadIdx.x;
  if (c4 >= N_VOCAB / 4) return;
  float s = sscale[row];
  ushort4 v = *(const ushort4*)(Eb + (size_t)row * N_VOCAB + c4 * 4u);
  float4 o;
  o.x = bf16_to_f32(v.x) * s;
  o.y = bf16_to_f32(v.y) * s;
  o.z = bf16_to_f32(v.z) * s;
  o.w = bf16_to_f32(v.w) * s;
  *(float4*)(out + (size_t)row * OUT_PITCH + c4 * 4u) = o;
}

// ---------- K3b: in-place scale (fallback) ----------
__global__ void scale_kernel(float4* __restrict__ out, const float* __restrict__ sscale) {
  const unsigned total = M_ROWS * (N_VOCAB / 4);
  unsigned stride = gridDim.x * blockDim.x;
  for (unsigned i = blockIdx.x * blockDim.x + threadIdx.x; i < total; i += stride) {
    unsigned r = i / (N_VOCAB / 4);
    unsigned c = i % (N_VOCAB / 4);
    float s = sscale[r];
    float4 v = out[(size_t)r * (OUT_PITCH / 4) + c];
    v.x *= s; v.y *= s; v.z *= s; v.w *= s;
    out[(size_t)r * (OUT_PITCH / 4) + c] = v;
  }
}

// ---------- K4: copy branch scatter ----------
__global__ void copyprob_kernel(const float* __restrict__ attn, const int* __restrict__ src_ids,
                                const float* __restrict__ copyg, float* __restrict__ out) {
  unsigned r = blockIdx.x;
  unsigned tid = threadIdx.x;
  __shared__ float cp[CV_DIM];
  for (unsigned v = tid; v < CV_DIM; v += 128) cp[v] = 0.f;
  __syncthreads();
  unsigned batch = r >> 7;
  float g = copyg[r];
  for (unsigned s = tid; s < S_DIM; s += 128) {
    float a = attn[(size_t)r * S_DIM + s] * g;
    atomicAdd(&cp[src_ids[batch * S_DIM + s]], a);
  }
  __syncthreads();
  for (unsigned v = tid; v < CV_DIM; v += 128)
    out[(size_t)r * OUT_PITCH + N_VOCAB + v] = cp[v];
}

extern "C" void kernel_launch(void* const* d_in, const int* in_sizes, int n_in,
                              void* d_out, int out_size, void* d_ws, size_t ws_size,
                              hipStream_t stream) {
  const float* hidden    = (const float*)d_in[0];
  const float* copy_attn = (const float*)d_in[1];
  const float* src_map   = (const float*)d_in[2];
  const float* W         = (const float*)d_in[3];
  const float* bias      = (const float*)d_in[4];
  const float* w_copy    = (const float*)d_in[5];
  const float* b_copy    = (const float*)d_in[6];
  float* out = (float*)d_out;

  char* ws = (char*)d_ws;
  unsigned short* Wb = (unsigned short*)(ws + WB_OFF);
  unsigned short* Hb = (unsigned short*)(ws + HB_OFF);
  float* copyg   = (float*)(ws + COPYG_OFF);
  float* row_sum = (float*)(ws + RSUM_OFF);
  float* sscale  = (float*)(ws + SSCALE_OFF);
  int*   src_ids = (int*)(ws + SRCID_OFF);
  unsigned short* Eb = (unsigned short*)(ws + EB_OFF);

  const bool bf16_path = (ws_size >= WS_NEED_BF16);

  hipMemsetAsync(row_sum, 0, M_ROWS * sizeof(float), stream);

  cvt_kernel<<<2048, 256, 0, stream>>>((const float4*)W, (ushort4*)Wb,
                                       (unsigned)(N_VOCAB * K_DIM / 4));
  cvt_kernel<<<1024, 256, 0, stream>>>((const float4*)hidden, (ushort4*)Hb,
                                       (unsigned)(M_ROWS * K_DIM / 4));
  copygate_kernel<<<M_ROWS / 4, 256, 0, stream>>>(hidden, w_copy, b_copy, copyg);
  srcids_kernel<<<(32 * S_DIM) / 4, 256, 0, stream>>>(src_map, src_ids);

  // main GEMM: 32 x 250 tiles of 128x128, 256 threads, 3 blocks/CU
  if (bf16_path) {
    gemm_exp_kernel<1><<<(M_ROWS / 128) * (N_VOCAB / 128), 256, 0, stream>>>(
        Hb, Wb, bias, out, Eb, row_sum);
  } else {
    gemm_exp_kernel<0><<<(M_ROWS / 128) * (N_VOCAB / 128), 256, 0, stream>>>(
        Hb, Wb, bias, out, Eb, row_sum);
  }

  finalize_kernel<<<(M_ROWS + 255) / 256, 256, 0, stream>>>(row_sum, copyg, sscale);

  if (bf16_path) {
    dim3 g((N_VOCAB / 4 + 255) / 256, M_ROWS);
    scale_bf16_kernel<<<g, 256, 0, stream>>>(Eb, sscale, out);
  } else {
    scale_kernel<<<4096, 256, 0, stream>>>((float4*)out, sscale);
  }

  copyprob_kernel<<<M_ROWS, 128, 0, stream>>>(copy_attn, src_ids, copyg, out);
}

// Round 5
// 431.266 us; speedup vs baseline: 1.3938x; 1.1285x over previous
//
#include <hip/hip_runtime.h>
#include <hip/hip_bf16.h>
#include <cstdint>
#include <cstddef>

// Problem dims
#define M_ROWS   4096     // B*T
#define N_VOCAB  32000    // V
#define K_DIM    512      // D
#define S_DIM    400
#define CV_DIM   600
#define OUT_PITCH 32600   // V + CV
#define PAD_IDX  1

typedef __attribute__((ext_vector_type(8))) short short8;
typedef __attribute__((ext_vector_type(8))) unsigned short ushort8;
typedef __attribute__((ext_vector_type(4))) float f32x4;

// ws layout
#define WB_OFF   0ull                       // W bf16: 32,768,000 B
#define HB_OFF   32768000ull                // hidden bf16: 4,194,304 B
#define COPYG_OFF 36962304ull
#define RSUM_OFF  36978688ull
#define SSCALE_OFF 36995072ull
#define SRCID_OFF 37011456ull               // 51,200 B
#define EB_OFF    37062656ull               // bf16 exp intermediate: 262,144,000 B
#define WS_NEED_BF16 (EB_OFF + 262144000ull)

__device__ inline void gload_lds16(const void* g, void* l) {
  __builtin_amdgcn_global_load_lds(
      (const __attribute__((address_space(1))) unsigned int*)g,
      (__attribute__((address_space(3))) unsigned int*)l, 16, 0, 0);
}

__device__ inline unsigned short f32_to_bf16_rn(float f) {
  unsigned u = __float_as_uint(f);
  u += 0x7FFFu + ((u >> 16) & 1u);
  return (unsigned short)(u >> 16);
}
__device__ inline float bf16_to_f32(unsigned short h) {
  return __uint_as_float((unsigned)h << 16);
}

// ---------- K1a: fp32 -> bf16 conversion (vectorized) ----------
__global__ void cvt_kernel(const float4* __restrict__ in, ushort4* __restrict__ out, unsigned n4) {
  unsigned stride = gridDim.x * blockDim.x;
  for (unsigned i = blockIdx.x * blockDim.x + threadIdx.x; i < n4; i += stride) {
    float4 v = in[i];
    ushort4 o;
    o.x = f32_to_bf16_rn(v.x);
    o.y = f32_to_bf16_rn(v.y);
    o.z = f32_to_bf16_rn(v.z);
    o.w = f32_to_bf16_rn(v.w);
    out[i] = o;
  }
}

// ---------- K1b: copy gate ----------
__global__ void copygate_kernel(const float* __restrict__ hidden, const float* __restrict__ w_copy,
                                const float* __restrict__ b_copy, float* __restrict__ copyg) {
  unsigned gw = (blockIdx.x * blockDim.x + threadIdx.x) >> 6;
  unsigned lane = threadIdx.x & 63u;
  if (gw >= M_ROWS) return;
  const float4* h4 = (const float4*)(hidden + (size_t)gw * K_DIM);
  const float4* w4 = (const float4*)w_copy;
  float dot = 0.f;
  #pragma unroll
  for (int i = 0; i < 2; ++i) {
    float4 a = h4[lane * 2 + i], w = w4[lane * 2 + i];
    dot += a.x * w.x + a.y * w.y + a.z * w.z + a.w * w.w;
  }
  #pragma unroll
  for (int mask = 1; mask < 64; mask <<= 1) dot += __shfl_xor(dot, mask);
  if (lane == 0) copyg[gw] = 1.f / (1.f + __expf(-(dot + b_copy[0])));
}

// ---------- K1c: recover src_ids from one-hot src_map ----------
__global__ void srcids_kernel(const float* __restrict__ src_map, int* __restrict__ src_ids) {
  unsigned pos = (blockIdx.x * blockDim.x + threadIdx.x) >> 6;
  unsigned lane = threadIdx.x & 63u;
  if (pos >= 32 * S_DIM) return;
  const float* row = src_map + (size_t)pos * CV_DIM;
  int found = 1 << 30;
  for (int v = lane; v < CV_DIM; v += 64)
    if (row[v] > 0.5f) found = v;
  #pragma unroll
  for (int mask = 1; mask < 64; mask <<= 1) {
    int o = __shfl_xor(found, mask);
    found = found < o ? found : o;
  }
  if (lane == 0) src_ids[pos] = found;
}

// ---------- K2: m97-structure 128x128 bf16 MFMA GEMM + exp epilogue ----------
// 4 waves (2x2), BK=64, single 32 KB LDS, 2-barrier loop, T2 swizzled LDS,
// 4 blocks/CU (launch_bounds caps VGPR<=128). BF16OUT=1 path has NO atomics:
// row sums are computed later in norm_scale_kernel (which re-reads Eb anyway).
template<int BF16OUT>
__global__ __launch_bounds__(256, 4)
void gemm_exp_kernel(const unsigned short* __restrict__ A,
                     const unsigned short* __restrict__ B,
                     const float* __restrict__ bias,
                     float* __restrict__ out,
                     unsigned short* __restrict__ Eb,
                     float* __restrict__ row_sum) {
  // As/Bs: [128 rows][8 chunks swz][8 ushort] = 16 KB each; reused for epilogue pack.
  __shared__ unsigned short smem[16384];   // 32 KB
  unsigned short* As = smem;
  unsigned short* Bs = smem + 8192;

  unsigned bid = blockIdx.x;
  // bijective XCD swizzle: 8000 blocks, 8000 % 8 == 0
  unsigned wg = (bid & 7u) * 1000u + (bid >> 3);
  unsigned mt = wg / 250u, nt = wg % 250u;
  unsigned m0 = mt * 128u, n0 = nt * 128u;
  unsigned tid = threadIdx.x;
  unsigned lane = tid & 63u;
  unsigned wid = tid >> 6;
  unsigned wm = wid >> 1, wn = wid & 1u;    // 2 x 2 wave grid, 64x64 per wave
  unsigned lr = lane >> 4, lc = lane & 15u;

  // swizzled read chunk offsets (ushort units) for ks=0/1
  const unsigned ch0 = (lr ^ (lc & 7u)) * 8u;
  const unsigned ch1 = ((lr + 4u) ^ (lc & 7u)) * 8u;

  // staging sources (kt-invariant): unit u = i*256 + tid, rr = u>>3, inverse-swz chunk
  const unsigned short* Asrc[4];
  const unsigned short* Bsrc[4];
  unsigned dst[4];
  #pragma unroll
  for (unsigned i = 0; i < 4; ++i) {
    unsigned u = i * 256u + tid;
    unsigned rr = u >> 3;                       // 0..127
    unsigned ch = (u & 7u) ^ (rr & 7u);         // inverse-swizzled source chunk
    dst[i] = u * 16u;                           // linear dest byte offset
    Asrc[i] = A + (size_t)(m0 + rr) * K_DIM + ch * 8u;
    Bsrc[i] = B + (size_t)(n0 + rr) * K_DIM + ch * 8u;
  }
  // fragment read row bases (ushort index)
  unsigned arow[4], brow[4];
  #pragma unroll
  for (int m = 0; m < 4; ++m) arow[m] = (wm * 64u + m * 16u + lc) * 64u;
  #pragma unroll
  for (int n = 0; n < 4; ++n) brow[n] = (wn * 64u + n * 16u + lc) * 64u;

  f32x4 acc[4][4] = {};

  for (unsigned kt = 0; kt < 8; ++kt) {
    unsigned k0 = kt * 64u;
    #pragma unroll
    for (unsigned i = 0; i < 4; ++i) {
      gload_lds16(Asrc[i] + k0, (char*)As + dst[i]);
      gload_lds16(Bsrc[i] + k0, (char*)Bs + dst[i]);
    }
    __syncthreads();   // compiler emits vmcnt(0) drain before barrier
    {
      short8 af[4][2], bf[4][2];
      #pragma unroll
      for (int m = 0; m < 4; ++m) {
        af[m][0] = *(const short8*)&As[arow[m] + ch0];
        af[m][1] = *(const short8*)&As[arow[m] + ch1];
      }
      #pragma unroll
      for (int n = 0; n < 4; ++n) {
        bf[n][0] = *(const short8*)&Bs[brow[n] + ch0];
        bf[n][1] = *(const short8*)&Bs[brow[n] + ch1];
      }
      #pragma unroll
      for (int ks = 0; ks < 2; ++ks)
        #pragma unroll
        for (int m = 0; m < 4; ++m)
          #pragma unroll
          for (int n = 0; n < 4; ++n)
            acc[m][n] = __builtin_amdgcn_mfma_f32_16x16x32_bf16(af[m][ks], bf[n][ks],
                                                                acc[m][n], 0, 0, 0);
    }
    __syncthreads();
  }

  // epilogue: e = exp(logit + bias); |logit| <~ 4 so no max-subtraction.
  float bv[4];
  #pragma unroll
  for (int n = 0; n < 4; ++n) bv[n] = bias[n0 + wn * 64u + n * 16u + lc];

  if (BF16OUT) {
    // exp + pack 128x128 bf16 tile via LDS (swizzled), coalesced stores to Eb.
    // NO row-sum atomics here; norm_scale_kernel computes sums on its re-read.
    #pragma unroll
    for (int m = 0; m < 4; ++m)
      #pragma unroll
      for (int j = 0; j < 4; ++j) {
        unsigned r = wm * 64u + m * 16u + lr * 4u + j;
        #pragma unroll
        for (int n = 0; n < 4; ++n) {
          unsigned c = wn * 64u + n * 16u + lc;
          unsigned gcol = n0 + c;
          float e = (gcol == PAD_IDX) ? 0.f : __expf(acc[m][n][j] + bv[n]);
          smem[r * 128u + (c ^ ((r & 7u) << 3))] = f32_to_bf16_rn(e);
        }
      }
    __syncthreads();
    {
      unsigned r = tid >> 1, c0 = (tid & 1u) * 64u;
      unsigned short* gdst = Eb + (size_t)(m0 + r) * N_VOCAB + n0 + c0;
      #pragma unroll
      for (unsigned q = 0; q < 8; ++q) {
        ushort8 v = *(const ushort8*)&smem[r * 128u + c0 + ((q ^ (r & 7u)) << 3)];
        *(ushort8*)(gdst + q * 8u) = v;
      }
    }
  } else {
    // fallback: fp32 stores + atomic row sums (old flow)
    #pragma unroll
    for (int m = 0; m < 4; ++m) {
      #pragma unroll
      for (int j = 0; j < 4; ++j) {
        unsigned grow = m0 + wm * 64u + m * 16u + lr * 4u + j;
        float rs = 0.f;
        #pragma unroll
        for (int n = 0; n < 4; ++n) {
          unsigned gcol = n0 + wn * 64u + n * 16u + lc;
          float e = (gcol == PAD_IDX) ? 0.f : __expf(acc[m][n][j] + bv[n]);
          out[(size_t)grow * OUT_PITCH + gcol] = e;
          rs += e;
        }
        #pragma unroll
        for (int mask = 1; mask < 16; mask <<= 1) rs += __shfl_xor(rs, mask);
        if (lc == 0) atomicAdd(&row_sum[grow], rs);
      }
    }
  }
}

// ---------- K3: per-row sum + scale: out = Eb * (1-gate)/sum ----------
// One block per row. Row (62.5 KB bf16) loaded to registers (static unroll),
// block tree-reduce for the sum, then scale+store fp32. No atomics anywhere.
__global__ __launch_bounds__(256)
void norm_scale_kernel(const unsigned short* __restrict__ Eb,
                       const float* __restrict__ copyg,
                       float* __restrict__ out) {
  unsigned r = blockIdx.x;
  unsigned tid = threadIdx.x;
  const ushort8* src = (const ushort8*)(Eb + (size_t)r * N_VOCAB);   // 4000 chunks
  ushort8 v[16];
  float lsum = 0.f;
  #pragma unroll
  for (int i = 0; i < 16; ++i) {
    unsigned c = (unsigned)i * 256u + tid;
    if (c < 4000u) {
      v[i] = src[c];
      #pragma unroll
      for (int k = 0; k < 8; ++k) lsum += bf16_to_f32(v[i][k]);
    }
  }
  #pragma unroll
  for (int mask = 1; mask < 64; mask <<= 1) lsum += __shfl_xor(lsum, mask);
  __shared__ float wsum[4];
  if ((tid & 63u) == 0) wsum[tid >> 6] = lsum;
  __syncthreads();
  float s = (1.f - copyg[r]) / (wsum[0] + wsum[1] + wsum[2] + wsum[3]);
  float* dst = out + (size_t)r * OUT_PITCH;
  #pragma unroll
  for (int i = 0; i < 16; ++i) {
    unsigned c = (unsigned)i * 256u + tid;
    if (c < 4000u) {
      float4 lo, hi;
      lo.x = bf16_to_f32(v[i][0]) * s; lo.y = bf16_to_f32(v[i][1]) * s;
      lo.z = bf16_to_f32(v[i][2]) * s; lo.w = bf16_to_f32(v[i][3]) * s;
      hi.x = bf16_to_f32(v[i][4]) * s; hi.y = bf16_to_f32(v[i][5]) * s;
      hi.z = bf16_to_f32(v[i][6]) * s; hi.w = bf16_to_f32(v[i][7]) * s;
      float4* o = (float4*)(dst + c * 8u);
      o[0] = lo; o[1] = hi;
    }
  }
}

// ---------- fallback-path kernels ----------
__global__ void finalize_kernel(const float* __restrict__ row_sum, const float* __restrict__ copyg,
                                float* __restrict__ sscale) {
  unsigned r = blockIdx.x * blockDim.x + threadIdx.x;
  if (r < M_ROWS) sscale[r] = (1.f - copyg[r]) / row_sum[r];
}

__global__ void scale_kernel(float4* __restrict__ out, const float* __restrict__ sscale) {
  const unsigned total = M_ROWS * (N_VOCAB / 4);
  unsigned stride = gridDim.x * blockDim.x;
  for (unsigned i = blockIdx.x * blockDim.x + threadIdx.x; i < total; i += stride) {
    unsigned r = i / (N_VOCAB / 4);
    unsigned c = i % (N_VOCAB / 4);
    float s = sscale[r];
    float4 v = out[(size_t)r * (OUT_PITCH / 4) + c];
    v.x *= s; v.y *= s; v.z *= s; v.w *= s;
    out[(size_t)r * (OUT_PITCH / 4) + c] = v;
  }
}

// ---------- K4: copy branch scatter ----------
__global__ void copyprob_kernel(const float* __restrict__ attn, const int* __restrict__ src_ids,
                                const float* __restrict__ copyg, float* __restrict__ out) {
  unsigned r = blockIdx.x;
  unsigned tid = threadIdx.x;
  __shared__ float cp[CV_DIM];
  for (unsigned v = tid; v < CV_DIM; v += 128) cp[v] = 0.f;
  __syncthreads();
  unsigned batch = r >> 7;
  float g = copyg[r];
  for (unsigned s = tid; s < S_DIM; s += 128) {
    float a = attn[(size_t)r * S_DIM + s] * g;
    atomicAdd(&cp[src_ids[batch * S_DIM + s]], a);
  }
  __syncthreads();
  for (unsigned v = tid; v < CV_DIM; v += 128)
    out[(size_t)r * OUT_PITCH + N_VOCAB + v] = cp[v];
}

extern "C" void kernel_launch(void* const* d_in, const int* in_sizes, int n_in,
                              void* d_out, int out_size, void* d_ws, size_t ws_size,
                              hipStream_t stream) {
  const float* hidden    = (const float*)d_in[0];
  const float* copy_attn = (const float*)d_in[1];
  const float* src_map   = (const float*)d_in[2];
  const float* W         = (const float*)d_in[3];
  const float* bias      = (const float*)d_in[4];
  const float* w_copy    = (const float*)d_in[5];
  const float* b_copy    = (const float*)d_in[6];
  float* out = (float*)d_out;

  char* ws = (char*)d_ws;
  unsigned short* Wb = (unsigned short*)(ws + WB_OFF);
  unsigned short* Hb = (unsigned short*)(ws + HB_OFF);
  float* copyg   = (float*)(ws + COPYG_OFF);
  float* row_sum = (float*)(ws + RSUM_OFF);
  float* sscale  = (float*)(ws + SSCALE_OFF);
  int*   src_ids = (int*)(ws + SRCID_OFF);
  unsigned short* Eb = (unsigned short*)(ws + EB_OFF);

  const bool bf16_path = (ws_size >= WS_NEED_BF16);

  cvt_kernel<<<2048, 256, 0, stream>>>((const float4*)W, (ushort4*)Wb,
                                       (unsigned)(N_VOCAB * K_DIM / 4));
  cvt_kernel<<<1024, 256, 0, stream>>>((const float4*)hidden, (ushort4*)Hb,
                                       (unsigned)(M_ROWS * K_DIM / 4));
  copygate_kernel<<<M_ROWS / 4, 256, 0, stream>>>(hidden, w_copy, b_copy, copyg);
  srcids_kernel<<<(32 * S_DIM) / 4, 256, 0, stream>>>(src_map, src_ids);

  if (bf16_path) {
    gemm_exp_kernel<1><<<(M_ROWS / 128) * (N_VOCAB / 128), 256, 0, stream>>>(
        Hb, Wb, bias, out, Eb, row_sum);
    norm_scale_kernel<<<M_ROWS, 256, 0, stream>>>(Eb, copyg, out);
  } else {
    hipMemsetAsync(row_sum, 0, M_ROWS * sizeof(float), stream);
    gemm_exp_kernel<0><<<(M_ROWS / 128) * (N_VOCAB / 128), 256, 0, stream>>>(
        Hb, Wb, bias, out, Eb, row_sum);
    finalize_kernel<<<(M_ROWS + 255) / 256, 256, 0, stream>>>(row_sum, copyg, sscale);
    scale_kernel<<<4096, 256, 0, stream>>>((float4*)out, sscale);
  }

  copyprob_kernel<<<M_ROWS, 128, 0, stream>>>(copy_attn, src_ids, copyg, out);
}